// Round 1
// baseline (360.133 us; speedup 1.0000x reference)
//
#include <hip/hip_runtime.h>

// Problem: result = sum_i | sum_j flow[i,j] - sum_j flow[j,i] |, N=8192, fp32.
// Memory-bound: one 256 MiB pass. Strategy: single streaming kernel builds
// diff[i] = row_sum[i] - col_sum[i] via atomics into d_ws, tiny reduce kernel
// computes sum(|diff|) into d_out[0].

constexpr int N = 8192;

// Tile: 64 rows x 256 cols per block. 256 threads = 4 waves.
// wave w handles rows (row0 + w + 4k), k=0..15; lane l owns float4 column col4.
__global__ __launch_bounds__(256) void tile_sums_kernel(
    const float* __restrict__ flow, float* __restrict__ diff) {
  const int wave = threadIdx.x >> 6;
  const int lane = threadIdx.x & 63;
  const int col4 = blockIdx.x * 64 + lane;  // float4 column index
  const int col  = col4 * 4;
  const int row0 = blockIdx.y * 64 + wave;

  const float4* __restrict__ flow4 = reinterpret_cast<const float4*>(flow);

  float4 colacc = make_float4(0.f, 0.f, 0.f, 0.f);

#pragma unroll
  for (int k = 0; k < 16; ++k) {
    const int r = row0 + k * 4;
    float4 v = flow4[(size_t)r * (N / 4) + col4];
    colacc.x += v.x; colacc.y += v.y; colacc.z += v.z; colacc.w += v.w;

    float rs = (v.x + v.y) + (v.z + v.w);
    // wave-wide (64-lane) reduction
#pragma unroll
    for (int off = 32; off > 0; off >>= 1)
      rs += __shfl_down(rs, off, 64);
    if (lane == 0) atomicAdd(&diff[r], rs);
  }

  // Reduce column partials across the 4 waves in LDS, then one atomic per col.
  __shared__ float4 lds[4][64];
  lds[wave][lane] = colacc;
  __syncthreads();
  if (wave == 0) {
    float4 a = lds[0][lane], b = lds[1][lane], c = lds[2][lane], d = lds[3][lane];
    float sx = (a.x + b.x) + (c.x + d.x);
    float sy = (a.y + b.y) + (c.y + d.y);
    float sz = (a.z + b.z) + (c.z + d.z);
    float sw = (a.w + b.w) + (c.w + d.w);
    atomicAdd(&diff[col + 0], -sx);
    atomicAdd(&diff[col + 1], -sy);
    atomicAdd(&diff[col + 2], -sz);
    atomicAdd(&diff[col + 3], -sw);
  }
}

__global__ __launch_bounds__(256) void abs_reduce_kernel(
    const float* __restrict__ diff, float* __restrict__ out) {
  const float4* __restrict__ d4 = reinterpret_cast<const float4*>(diff);
  float s = 0.f;
#pragma unroll
  for (int i = threadIdx.x; i < N / 4; i += 256) {
    float4 v = d4[i];
    s += (fabsf(v.x) + fabsf(v.y)) + (fabsf(v.z) + fabsf(v.w));
  }
#pragma unroll
  for (int off = 32; off > 0; off >>= 1)
    s += __shfl_down(s, off, 64);

  __shared__ float wsum[4];
  if ((threadIdx.x & 63) == 0) wsum[threadIdx.x >> 6] = s;
  __syncthreads();
  if (threadIdx.x == 0) out[0] = (wsum[0] + wsum[1]) + (wsum[2] + wsum[3]);
}

extern "C" void kernel_launch(void* const* d_in, const int* in_sizes, int n_in,
                              void* d_out, int out_size, void* d_ws, size_t ws_size,
                              hipStream_t stream) {
  const float* flow = (const float*)d_in[0];
  float* out = (float*)d_out;
  float* diff = (float*)d_ws;  // N floats = 32 KB

  // d_ws is poisoned 0xAA before every call — zero it.
  hipMemsetAsync(diff, 0, (size_t)N * sizeof(float), stream);

  dim3 grid(N / 256, N / 64);  // (32, 128) = 4096 blocks
  tile_sums_kernel<<<grid, 256, 0, stream>>>(flow, diff);
  abs_reduce_kernel<<<1, 256, 0, stream>>>(diff, out);
}